// Round 4
// baseline (123.936 us; speedup 1.0000x reference)
//
#include <hip/hip_runtime.h>
#include <hip/hip_fp16.h>

// Ultimus: out = x + softmax((x@Kw+Kb)@(x@Qw+Qb)^T / sqrt(8)) @ (x@Vw+Vb) @ Zw + Zb
// N=8192, D_IN=48, D_ATTN=8, fp32 in/out.
//
// R15: R13 (34us) is LDS-pipe bound: 2.1M uniform ds_read_b128 x ~12cy on the
// per-CU LDS pipe (4 SIMDs share 1 pipe -> 4x oversubscribed vs the 9us VALU
// floor). R14 (4 rows/lane via LDS, ~41us) had the right amortization but
// __launch_bounds__(256,4)'s 128-VGPR cap forced spills (live set ~130).
// R15 keeps 4 rows/lane but removes LDS from the main loop entirely:
//  - each lane holds ONE pair's 16 dwords in VGPRs (4 coalesced dwordx4),
//  - per-pair broadcast = 16 x v_readlane into SGPRs (register-only; pk_fma
//    takes 1 SGPR operand legally). No barriers, no LDS, no memory in loop.
// Live VGPRs ~105 (kd 32 + acc 32 + tile 16 + misc) -> no cap, no spill,
// 4 waves/SIMD. Est. ~100 wave-instrs per 32-pair visit -> ~11us VALU-bound.
// LDS (36.9KB) only for the final 4-wave merge.
//
//  - Bound-softmax (Cauchy-Schwarz row bound) => fixed per-row exponent
//    shift; partials over disjoint j-chunks combine by pure addition.
//  - QV pair-interleaved: dword c of pair p = half2(val[2p][c], val[2p+1][c])
//    so one pk_fma accumulates scores for both j's of the pair at once.
//
// ws layout (floats):
//   [0, 32768)      Xksf16[8192] 8 f16/row (k * log2e/sqrt(8)), uint4/row
//   [32768, 98304)  QV per pair p: 16 dwords = q2pair[8] | v2pair[8]
//   [98304, 98560)  bmax[256] per-proj-block max ||q||^2 (plain store)
//   [98560, ...)    part[nch][8192][9] f32 partials: acc[0:8], l at [8]

#define QV_OFF   32768
#define BMAX_OFF 98304
#define PART_OFF 98560

typedef _Float16 hv2 __attribute__((ext_vector_type(2)));
union HVU { unsigned u; hv2 v; };

static __device__ __forceinline__ unsigned pku(float a, float b) {
    auto t = __builtin_amdgcn_cvt_pkrtz(a, b);
    union { decltype(t) x; unsigned u; } c; c.x = t; return c.u;
}
static __device__ __forceinline__ hv2 asV(unsigned u) { HVU t; t.u = u; return t.v; }
static __device__ __forceinline__ hv2 h2fma(hv2 a, hv2 b, hv2 c) {
#if __has_builtin(__builtin_elementwise_fma)
    return __builtin_elementwise_fma(a, b, c);
#else
    union { hv2 v; __half2 h; } A, B, C, D;
    A.v = a; B.v = b; C.v = c;
    D.h = __hfma2(A.h, B.h, C.h);
    return D.v;
#endif
}
static __device__ __forceinline__ unsigned dupL(unsigned u) {
    const unsigned lo = u & 0xFFFFu; return lo | (lo << 16);
}
static __device__ __forceinline__ unsigned dupH(unsigned u) {
    const unsigned hi = u >> 16; return hi | (hi << 16);
}

__global__ __launch_bounds__(256) void proj_kernel(
    const float* __restrict__ x,
    const float* __restrict__ Kw, const float* __restrict__ Kb,
    const float* __restrict__ Qw, const float* __restrict__ Qb,
    const float* __restrict__ Vw, const float* __restrict__ Vb,
    unsigned* __restrict__ Xksf16, unsigned* __restrict__ QV,
    float* __restrict__ bmax)
{
    __shared__ float xs[32 * 49];     // +1 pad
    __shared__ float wAll[3 * 388];   // stride 388 (mod 32 = 4) spreads 3 mats
    __shared__ float bs[24];
    __shared__ float outv[32][25];    // 24 cols + pad
    const int tid = threadIdx.x;
    const int r0 = blockIdx.x * 32;

    for (int i = tid; i < 1536; i += 256) {
        int r = i / 48, c = i - r * 48;
        xs[r * 49 + c] = x[r0 * 48 + i];
    }
    for (int i = tid; i < 384; i += 256) {
        wAll[i]       = Kw[i];
        wAll[388 + i] = Qw[i];
        wAll[776 + i] = Vw[i];
    }
    if (tid < 8)       bs[tid] = Kb[tid];
    else if (tid < 16) bs[tid] = Qb[tid - 8];
    else if (tid < 24) bs[tid] = Vb[tid - 16];
    __syncthreads();

    const int rl = tid >> 3;
    const int g  = tid & 7;
    const int c0 = 3 * g;
    const float* xr = &xs[rl * 49];
    const float* w0 = &wAll[((c0 + 0) >> 3) * 388 + ((c0 + 0) & 7)];
    const float* w1 = &wAll[((c0 + 1) >> 3) * 388 + ((c0 + 1) & 7)];
    const float* w2 = &wAll[((c0 + 2) >> 3) * 388 + ((c0 + 2) & 7)];
    float a0 = bs[c0], a1 = bs[c0 + 1], a2 = bs[c0 + 2];
    #pragma unroll
    for (int k = 0; k < 48; k++) {
        const float xv = xr[k];
        a0 = fmaf(xv, w0[k * 8], a0);
        a1 = fmaf(xv, w1[k * 8], a1);
        a2 = fmaf(xv, w2[k * 8], a2);
    }
    outv[rl][c0] = a0; outv[rl][c0 + 1] = a1; outv[rl][c0 + 2] = a2;
    __syncthreads();

    // QV pair-interleaved: pair p (16/block), col c (8), m: 0=q, 1=v
    {
        const int p = tid >> 4;
        const int c = (tid >> 1) & 7;
        const int m = tid & 1;
        const int col = (m ? 16 : 8) + c;
        QV[(blockIdx.x * 16 + p) * 16 + m * 8 + c] =
            pku(outv[2 * p][col], outv[2 * p + 1][col]);
    }
    const float kscale = 0.51008732149f;  // (1/sqrt(8)) * log2(e)
    if (tid < 32) {                       // K rows, f16 packed, pre-scaled
        uint4 o;
        o.x = pku(outv[tid][0] * kscale, outv[tid][1] * kscale);
        o.y = pku(outv[tid][2] * kscale, outv[tid][3] * kscale);
        o.z = pku(outv[tid][4] * kscale, outv[tid][5] * kscale);
        o.w = pku(outv[tid][6] * kscale, outv[tid][7] * kscale);
        ((uint4*)Xksf16)[r0 + tid] = o;
    }
    if (tid >= 192 && tid < 224) {        // block-max ||q||^2 (fp32)
        const int r = tid - 192;
        float n2 = 0.f;
        #pragma unroll
        for (int c = 0; c < 8; c++) n2 = fmaf(outv[r][8 + c], outv[r][8 + c], n2);
        #pragma unroll
        for (int off = 16; off > 0; off >>= 1)
            n2 = fmaxf(n2, __shfl_xor(n2, off, 64));
        if (r == 0) bmax[blockIdx.x] = n2;
    }
}

// grid = 32 row-groups (256 rows; 4 rows/lane) x nch j-chunks.
// Wave w handles pairs [(chunk*4 + w)*ppw, +ppw) in register tiles of 32:
// lane (l&31) owns pair (pb + (l&31))'s 16 dwords in VGPRs; per pair p the
// wave broadcasts them with 16 v_readlane (SGPR, register-only). No LDS and
// no barriers in the main loop. LDS only for the final 4-wave merge.
__global__ __launch_bounds__(256) void attn_kernel(
    const unsigned* __restrict__ Xksf16, const unsigned* __restrict__ QV,
    const float* __restrict__ bmax,
    float* __restrict__ part, int ppw)
{
    __shared__ float redf[4 * 256 * 9];   // 36,864B merge buffer

    const int tid  = threadIdx.x;
    const int lane = tid & 63;
    const int wv   = tid >> 6;
    const int rgrp  = blockIdx.x & 31;
    const int chunk = blockIdx.x >> 5;

    // qmax2 = max over 256 per-proj-block maxima
    float m = fmaxf(fmaxf(bmax[lane], bmax[64 + lane]),
                    fmaxf(bmax[128 + lane], bmax[192 + lane]));
    #pragma unroll
    for (int off = 32; off > 0; off >>= 1)
        m = fmaxf(m, __shfl_xor(m, off, 64));
    const float qmax2 = m;

    // 4 K-rows per lane: rows rgrp*256 + i*64 + lane (coalesced uint4 loads)
    unsigned kd[4][8];
    hv2 sinit2[4], l2[4], acc[4][8];
    const hv2 one2 = asV(0x3C003C00u);
    #pragma unroll
    for (int i = 0; i < 4; ++i) {
        const uint4 kv = ((const uint4*)Xksf16)[rgrp * 256 + i * 64 + lane];
        kd[i][0] = dupL(kv.x); kd[i][1] = dupH(kv.x);
        kd[i][2] = dupL(kv.y); kd[i][3] = dupH(kv.y);
        kd[i][4] = dupL(kv.z); kd[i][5] = dupH(kv.z);
        kd[i][6] = dupL(kv.w); kd[i][7] = dupH(kv.w);
        float kn2 = 0.f;
        #pragma unroll
        for (int c = 0; c < 8; c++) {
            const float kf = (float)asV(kd[i][c]).x;
            kn2 = fmaf(kf, kf, kn2);
        }
        const float sinit = -sqrtf(kn2 * qmax2);  // s <= -sinit: p in (0,~1]
        sinit2[i] = asV(pku(sinit, sinit));
        l2[i] = asV(0u);
        #pragma unroll
        for (int c = 0; c < 8; c++) acc[i][c] = asV(0u);
    }

    const uint4* QV4 = (const uint4*)QV;
    const int ntile = ppw >> 5;        // ppw is a multiple of 32

    for (int t = 0; t < ntile; ++t) {
        // stage: lane (l&31) owns pair pb + (l&31); 16 dwords in VGPRs.
        // (lanes 32..63 load duplicates -- harmless, keeps loads coalesced)
        const int pb = (chunk * 4 + wv) * ppw + t * 32 + (lane & 31);
        const uint4* src = QV4 + (size_t)pb * 4;
        const uint4 ta = src[0];   // q2pair c0..3
        const uint4 tb = src[1];   // q2pair c4..7
        const uint4 tc = src[2];   // v2pair c0..3
        const uint4 td = src[3];   // v2pair c4..7

        #pragma unroll 2
        for (int p = 0; p < 32; ++p) {
            unsigned qb[8], vb[8];
            qb[0] = (unsigned)__builtin_amdgcn_readlane((int)ta.x, p);
            qb[1] = (unsigned)__builtin_amdgcn_readlane((int)ta.y, p);
            qb[2] = (unsigned)__builtin_amdgcn_readlane((int)ta.z, p);
            qb[3] = (unsigned)__builtin_amdgcn_readlane((int)ta.w, p);
            qb[4] = (unsigned)__builtin_amdgcn_readlane((int)tb.x, p);
            qb[5] = (unsigned)__builtin_amdgcn_readlane((int)tb.y, p);
            qb[6] = (unsigned)__builtin_amdgcn_readlane((int)tb.z, p);
            qb[7] = (unsigned)__builtin_amdgcn_readlane((int)tb.w, p);
            vb[0] = (unsigned)__builtin_amdgcn_readlane((int)tc.x, p);
            vb[1] = (unsigned)__builtin_amdgcn_readlane((int)tc.y, p);
            vb[2] = (unsigned)__builtin_amdgcn_readlane((int)tc.z, p);
            vb[3] = (unsigned)__builtin_amdgcn_readlane((int)tc.w, p);
            vb[4] = (unsigned)__builtin_amdgcn_readlane((int)td.x, p);
            vb[5] = (unsigned)__builtin_amdgcn_readlane((int)td.y, p);
            vb[6] = (unsigned)__builtin_amdgcn_readlane((int)td.z, p);
            vb[7] = (unsigned)__builtin_amdgcn_readlane((int)td.w, p);
            #pragma unroll
            for (int i = 0; i < 4; ++i) {
                hv2 s2 = sinit2[i];
                s2 = h2fma(asV(kd[i][0]), asV(qb[0]), s2);
                s2 = h2fma(asV(kd[i][1]), asV(qb[1]), s2);
                s2 = h2fma(asV(kd[i][2]), asV(qb[2]), s2);
                s2 = h2fma(asV(kd[i][3]), asV(qb[3]), s2);
                s2 = h2fma(asV(kd[i][4]), asV(qb[4]), s2);
                s2 = h2fma(asV(kd[i][5]), asV(qb[5]), s2);
                s2 = h2fma(asV(kd[i][6]), asV(qb[6]), s2);
                s2 = h2fma(asV(kd[i][7]), asV(qb[7]), s2);
                const float pa  = __builtin_amdgcn_exp2f((float)s2.x);
                const float pbv = __builtin_amdgcn_exp2f((float)s2.y);
                const hv2 ph = asV(pku(pa, pbv));
                l2[i] = h2fma(ph, one2, l2[i]);
                acc[i][0] = h2fma(ph, asV(vb[0]), acc[i][0]);
                acc[i][1] = h2fma(ph, asV(vb[1]), acc[i][1]);
                acc[i][2] = h2fma(ph, asV(vb[2]), acc[i][2]);
                acc[i][3] = h2fma(ph, asV(vb[3]), acc[i][3]);
                acc[i][4] = h2fma(ph, asV(vb[4]), acc[i][4]);
                acc[i][5] = h2fma(ph, asV(vb[5]), acc[i][5]);
                acc[i][6] = h2fma(ph, asV(vb[6]), acc[i][6]);
                acc[i][7] = h2fma(ph, asV(vb[7]), acc[i][7]);
            }
        }
    }

    // merge the block's 4 waves via LDS
    #pragma unroll
    for (int i = 0; i < 4; ++i) {
        const int r = i * 64 + lane;
        #pragma unroll
        for (int c = 0; c < 8; c++)
            redf[(wv * 256 + r) * 9 + c] = (float)acc[i][c].x + (float)acc[i][c].y;
        redf[(wv * 256 + r) * 9 + 8] = (float)l2[i].x + (float)l2[i].y;
    }
    __syncthreads();
    for (int e = tid; e < 2304; e += 256) {
        const int r = e / 9, c = e - r * 9;
        const float s = redf[(0 * 256 + r) * 9 + c] + redf[(1 * 256 + r) * 9 + c]
                      + redf[(2 * 256 + r) * 9 + c] + redf[(3 * 256 + r) * 9 + c];
        part[((size_t)chunk * 8192 + rgrp * 256 + r) * 9 + c] = s;
    }
}

// 256 blocks x 32 rows; reduction parallelized over all 256 threads
// (thread = (row, col)), so nch=32 partial sets stay cheap.
__global__ __launch_bounds__(256) void finish_kernel(
    const float* __restrict__ x,
    const float* __restrict__ Zw, const float* __restrict__ Zb,
    const float* __restrict__ part, float* __restrict__ out, int nch)
{
    __shared__ float Zs[32 * 9];
    __shared__ float Zl[32];
    __shared__ float zw_s[384];
    __shared__ float zb_s[48];
    const int tid = threadIdx.x;
    const int r0 = blockIdx.x * 32;

    for (int i = tid; i < 384; i += 256) zw_s[i] = Zw[i];
    if (tid < 48) zb_s[tid] = Zb[tid];

    // phase 1: thread = (row r = tid>>3, col c = tid&7); c==0 also sums l
    {
        const int r = tid >> 3, c = tid & 7;
        float a = 0.f, l = 0.f;
        #pragma unroll 4
        for (int ch = 0; ch < nch; ch++) {
            const float* p = part + ((size_t)ch * 8192 + r0 + r) * 9;
            a += p[c];
            if (c == 0) l += p[8];
        }
        if (c == 0) Zl[r] = l;
        __syncthreads();
        Zs[r * 9 + c] = a * (1.0f / Zl[r]);
    }
    __syncthreads();

    for (int e = tid; e < 32 * 48; e += 256) {
        const int r = e / 48, c = e - r * 48;
        float o = x[r0 * 48 + e] + zb_s[c];
        #pragma unroll
        for (int k = 0; k < 8; k++) o = fmaf(Zs[r * 9 + k], zw_s[k * 48 + c], o);
        out[r0 * 48 + e] = o;
    }
}

extern "C" void kernel_launch(void* const* d_in, const int* in_sizes, int n_in,
                              void* d_out, int out_size, void* d_ws, size_t ws_size,
                              hipStream_t stream) {
    const float* x  = (const float*)d_in[0];
    const float* Kw = (const float*)d_in[1];
    const float* Kb = (const float*)d_in[2];
    const float* Qw = (const float*)d_in[3];
    const float* Qb = (const float*)d_in[4];
    const float* Vw = (const float*)d_in[5];
    const float* Vb = (const float*)d_in[6];
    const float* Zw = (const float*)d_in[7];
    const float* Zb = (const float*)d_in[8];
    float* out = (float*)d_out;

    float* ws = (float*)d_ws;
    unsigned* Xksf16 = (unsigned*)ws;
    unsigned* QV     = (unsigned*)(ws + QV_OFF);
    float* bmax      = ws + BMAX_OFF;
    float* part      = ws + PART_OFF;

    int nch = 32;
    const size_t avail = ws_size / 4;
    while (nch > 1 && (size_t)PART_OFF + (size_t)nch * 8192 * 9 > avail) nch >>= 1;
    const int ppw = 1024 / nch;   // j-pairs per wave (4096 pairs / (nch*4 waves))

    proj_kernel<<<256, 256, 0, stream>>>(x, Kw, Kb, Qw, Qb, Vw, Vb,
                                         Xksf16, QV, bmax);
    attn_kernel<<<32 * nch, 256, 0, stream>>>(Xksf16, QV, bmax, part, ppw);
    finish_kernel<<<256, 256, 0, stream>>>(x, Zw, Zb, part, out, nch);
}

// Round 5
// 118.445 us; speedup vs baseline: 1.0464x; 1.0464x over previous
//
#include <hip/hip_runtime.h>
#include <hip/hip_fp16.h>

// Ultimus: out = x + softmax((x@Kw+Kb)@(x@Qw+Qb)^T / sqrt(8)) @ (x@Vw+Vb) @ Zw + Zb
// N=8192, D_IN=48, D_ATTN=8, fp32 in/out.
//
// R16 = R14 (4 rows/lane, LDS-broadcast) with register pressure FIXED instead
// of capped. Evidence trail:
//   R13 (1 row/lane, LDS bcast)  = 34us : LDS-pipe bound (2.1M ds_read_b128
//        x ~12cy on the per-CU pipe = 41us theoretical; matches).
//   R14 (4 rows/lane, LDS bcast) = ~41us: right amortization, but
//        __launch_bounds__(256,4)'s 128-VGPR cap vs ~115-130 live set ->
//        scratch spills in the inner loop (3-4x blowup, the only mechanism
//        consistent with correct output + cost model of 10-12us).
//   R15 (readlane bcast)         = ~45us: broadcast moved ONTO the VALU
//        (16 readlane/pair, +20% instrs, no pipe overlap). Dead end.
// R16 changes vs R14: (1) __launch_bounds__(256) -- no min-waves clause, no
// VGPR cap (allocator free to use ~110-130; 3-4 waves/SIMD suffices);
// (2) unroll 1 on the pair loop (staging live set 32 -> 16 VGPR).
// Cost model: per block prologue ~1.5k + 32 pairs x ~85 instr x 2cy ~5.5k +
// merge ~2.5k cy; 1024 blocks, 3-4/CU resident -> attn ~5-10us.
//
//  - Bound-softmax (Cauchy-Schwarz row bound) => fixed per-row exponent
//    shift; partials over disjoint j-chunks combine by pure addition.
//  - QV pair-interleaved: dword c of pair p = half2(val[2p][c], val[2p+1][c])
//    so one pk_fma accumulates scores for both j's of the pair at once.
//
// ws layout (floats):
//   [0, 32768)      Xksf16[8192] 8 f16/row (k * log2e/sqrt(8)), uint4/row
//   [32768, 98304)  QV per pair p: 16 dwords = q2pair[8] | v2pair[8]
//   [98304, 98560)  bmax[256] per-proj-block max ||q||^2 (plain store)
//   [98560, ...)    part[nch][8192][9] f32 partials: acc[0:8], l at [8]

#define QV_OFF   32768
#define BMAX_OFF 98304
#define PART_OFF 98560

typedef _Float16 hv2 __attribute__((ext_vector_type(2)));
union HVU { unsigned u; hv2 v; };

static __device__ __forceinline__ unsigned pku(float a, float b) {
    auto t = __builtin_amdgcn_cvt_pkrtz(a, b);
    union { decltype(t) x; unsigned u; } c; c.x = t; return c.u;
}
static __device__ __forceinline__ hv2 asV(unsigned u) { HVU t; t.u = u; return t.v; }
static __device__ __forceinline__ hv2 h2fma(hv2 a, hv2 b, hv2 c) {
#if __has_builtin(__builtin_elementwise_fma)
    return __builtin_elementwise_fma(a, b, c);
#else
    union { hv2 v; __half2 h; } A, B, C, D;
    A.v = a; B.v = b; C.v = c;
    D.h = __hfma2(A.h, B.h, C.h);
    return D.v;
#endif
}
static __device__ __forceinline__ unsigned dupL(unsigned u) {
    const unsigned lo = u & 0xFFFFu; return lo | (lo << 16);
}
static __device__ __forceinline__ unsigned dupH(unsigned u) {
    const unsigned hi = u >> 16; return hi | (hi << 16);
}

__global__ __launch_bounds__(256) void proj_kernel(
    const float* __restrict__ x,
    const float* __restrict__ Kw, const float* __restrict__ Kb,
    const float* __restrict__ Qw, const float* __restrict__ Qb,
    const float* __restrict__ Vw, const float* __restrict__ Vb,
    unsigned* __restrict__ Xksf16, unsigned* __restrict__ QV,
    float* __restrict__ bmax)
{
    __shared__ float xs[32 * 49];     // +1 pad
    __shared__ float wAll[3 * 388];   // stride 388 (mod 32 = 4) spreads 3 mats
    __shared__ float bs[24];
    __shared__ float outv[32][25];    // 24 cols + pad
    const int tid = threadIdx.x;
    const int r0 = blockIdx.x * 32;

    for (int i = tid; i < 1536; i += 256) {
        int r = i / 48, c = i - r * 48;
        xs[r * 49 + c] = x[r0 * 48 + i];
    }
    for (int i = tid; i < 384; i += 256) {
        wAll[i]       = Kw[i];
        wAll[388 + i] = Qw[i];
        wAll[776 + i] = Vw[i];
    }
    if (tid < 8)       bs[tid] = Kb[tid];
    else if (tid < 16) bs[tid] = Qb[tid - 8];
    else if (tid < 24) bs[tid] = Vb[tid - 16];
    __syncthreads();

    const int rl = tid >> 3;
    const int g  = tid & 7;
    const int c0 = 3 * g;
    const float* xr = &xs[rl * 49];
    const float* w0 = &wAll[((c0 + 0) >> 3) * 388 + ((c0 + 0) & 7)];
    const float* w1 = &wAll[((c0 + 1) >> 3) * 388 + ((c0 + 1) & 7)];
    const float* w2 = &wAll[((c0 + 2) >> 3) * 388 + ((c0 + 2) & 7)];
    float a0 = bs[c0], a1 = bs[c0 + 1], a2 = bs[c0 + 2];
    #pragma unroll
    for (int k = 0; k < 48; k++) {
        const float xv = xr[k];
        a0 = fmaf(xv, w0[k * 8], a0);
        a1 = fmaf(xv, w1[k * 8], a1);
        a2 = fmaf(xv, w2[k * 8], a2);
    }
    outv[rl][c0] = a0; outv[rl][c0 + 1] = a1; outv[rl][c0 + 2] = a2;
    __syncthreads();

    // QV pair-interleaved: pair p (16/block), col c (8), m: 0=q, 1=v
    {
        const int p = tid >> 4;
        const int c = (tid >> 1) & 7;
        const int m = tid & 1;
        const int col = (m ? 16 : 8) + c;
        QV[(blockIdx.x * 16 + p) * 16 + m * 8 + c] =
            pku(outv[2 * p][col], outv[2 * p + 1][col]);
    }
    const float kscale = 0.51008732149f;  // (1/sqrt(8)) * log2(e)
    if (tid < 32) {                       // K rows, f16 packed, pre-scaled
        uint4 o;
        o.x = pku(outv[tid][0] * kscale, outv[tid][1] * kscale);
        o.y = pku(outv[tid][2] * kscale, outv[tid][3] * kscale);
        o.z = pku(outv[tid][4] * kscale, outv[tid][5] * kscale);
        o.w = pku(outv[tid][6] * kscale, outv[tid][7] * kscale);
        ((uint4*)Xksf16)[r0 + tid] = o;
    }
    if (tid >= 192 && tid < 224) {        // block-max ||q||^2 (fp32)
        const int r = tid - 192;
        float n2 = 0.f;
        #pragma unroll
        for (int c = 0; c < 8; c++) n2 = fmaf(outv[r][8 + c], outv[r][8 + c], n2);
        #pragma unroll
        for (int off = 16; off > 0; off >>= 1)
            n2 = fmaxf(n2, __shfl_xor(n2, off, 64));
        if (r == 0) bmax[blockIdx.x] = n2;
    }
}

// grid = 32 row-groups (256 rows; 4 rows/lane) x nch j-chunks.
// Wave w handles pairs [(chunk*4 + w)*ppw, +ppw) in tiles of 32 pairs.
// Per tile: block stages 4 waves x 32 pairs x 64B = 8KB into LDS (coalesced
// dwordx4), then each pair's 4 uniform ds_read_b128 feed 4 rows x 2 j's of
// score+PV math (amortizes the LDS-pipe per-instruction cost 4x vs R13).
// NO VGPR cap (R14's spill cause); unroll 1 keeps staging live set at 16.
__global__ __launch_bounds__(256) void attn_kernel(
    const unsigned* __restrict__ Xksf16, const unsigned* __restrict__ QV,
    const float* __restrict__ bmax,
    float* __restrict__ part, int ppw)
{
    __shared__ uint4 sh4[2304];        // 36,864B: slab[512] + red alias
    uint4* slab = sh4;
    float* redf = (float*)sh4;         // red[w][r][c] = redf[(w*256+r)*9+c]

    const int tid  = threadIdx.x;
    const int lane = tid & 63;
    const int wv   = tid >> 6;
    const int rgrp  = blockIdx.x & 31;
    const int chunk = blockIdx.x >> 5;

    // qmax2 = max over 256 per-proj-block maxima
    float m = fmaxf(fmaxf(bmax[lane], bmax[64 + lane]),
                    fmaxf(bmax[128 + lane], bmax[192 + lane]));
    #pragma unroll
    for (int off = 32; off > 0; off >>= 1)
        m = fmaxf(m, __shfl_xor(m, off, 64));
    const float qmax2 = m;

    // 4 K-rows per lane: rows rgrp*256 + i*64 + lane (coalesced uint4 loads)
    unsigned kd[4][8];
    hv2 sinit2[4], l2[4], acc[4][8];
    const hv2 one2 = asV(0x3C003C00u);
    #pragma unroll
    for (int i = 0; i < 4; ++i) {
        const uint4 kv = ((const uint4*)Xksf16)[rgrp * 256 + i * 64 + lane];
        kd[i][0] = dupL(kv.x); kd[i][1] = dupH(kv.x);
        kd[i][2] = dupL(kv.y); kd[i][3] = dupH(kv.y);
        kd[i][4] = dupL(kv.z); kd[i][5] = dupH(kv.z);
        kd[i][6] = dupL(kv.w); kd[i][7] = dupH(kv.w);
        float kn2 = 0.f;
        #pragma unroll
        for (int c = 0; c < 8; c++) {
            const float kf = (float)asV(kd[i][c]).x;
            kn2 = fmaf(kf, kf, kn2);
        }
        const float sinit = -sqrtf(kn2 * qmax2);  // s <= -sinit: p in (0,~1]
        sinit2[i] = asV(pku(sinit, sinit));
        l2[i] = asV(0u);
        #pragma unroll
        for (int c = 0; c < 8; c++) acc[i][c] = asV(0u);
    }

    const uint4* QV4 = (const uint4*)QV;
    const int nt = ppw >> 5;           // ppw is a multiple of 32

    for (int t = 0; t < nt; ++t) {
        // stage: wave w's 32-pair tile -> slab[w*128 .. w*128+128)
        for (int i = tid; i < 512; i += 256) {
            const int w = i >> 7;
            const int j = i & 127;
            slab[i] = QV4[(size_t)((((chunk * 4 + w) * ppw + (t << 5)) << 2) + j)];
        }
        __syncthreads();

        const uint4* sw = &slab[wv << 7];
        #pragma unroll 1
        for (int p = 0; p < 32; ++p) {
            const uint4 qp0 = sw[p * 4 + 0];   // q2pair c0..3
            const uint4 qp1 = sw[p * 4 + 1];   // q2pair c4..7
            const uint4 vp0 = sw[p * 4 + 2];   // v2pair c0..3
            const uint4 vp1 = sw[p * 4 + 3];   // v2pair c4..7
            #pragma unroll
            for (int i = 0; i < 4; ++i) {
                hv2 s2 = sinit2[i];
                s2 = h2fma(asV(kd[i][0]), asV(qp0.x), s2);
                s2 = h2fma(asV(kd[i][1]), asV(qp0.y), s2);
                s2 = h2fma(asV(kd[i][2]), asV(qp0.z), s2);
                s2 = h2fma(asV(kd[i][3]), asV(qp0.w), s2);
                s2 = h2fma(asV(kd[i][4]), asV(qp1.x), s2);
                s2 = h2fma(asV(kd[i][5]), asV(qp1.y), s2);
                s2 = h2fma(asV(kd[i][6]), asV(qp1.z), s2);
                s2 = h2fma(asV(kd[i][7]), asV(qp1.w), s2);
                const float pa = __builtin_amdgcn_exp2f((float)s2.x);
                const float pb = __builtin_amdgcn_exp2f((float)s2.y);
                const hv2 ph = asV(pku(pa, pb));
                l2[i] = h2fma(ph, one2, l2[i]);
                acc[i][0] = h2fma(ph, asV(vp0.x), acc[i][0]);
                acc[i][1] = h2fma(ph, asV(vp0.y), acc[i][1]);
                acc[i][2] = h2fma(ph, asV(vp0.z), acc[i][2]);
                acc[i][3] = h2fma(ph, asV(vp0.w), acc[i][3]);
                acc[i][4] = h2fma(ph, asV(vp1.x), acc[i][4]);
                acc[i][5] = h2fma(ph, asV(vp1.y), acc[i][5]);
                acc[i][6] = h2fma(ph, asV(vp1.z), acc[i][6]);
                acc[i][7] = h2fma(ph, asV(vp1.w), acc[i][7]);
            }
        }
        __syncthreads();   // all waves done reading slab before reuse
    }

    // merge the block's 4 waves via LDS (red aliases the slab)
    #pragma unroll
    for (int i = 0; i < 4; ++i) {
        const int r = i * 64 + lane;
        #pragma unroll
        for (int c = 0; c < 8; c++)
            redf[(wv * 256 + r) * 9 + c] = (float)acc[i][c].x + (float)acc[i][c].y;
        redf[(wv * 256 + r) * 9 + 8] = (float)l2[i].x + (float)l2[i].y;
    }
    __syncthreads();
    for (int e = tid; e < 2304; e += 256) {
        const int r = e / 9, c = e - r * 9;
        const float s = redf[(0 * 256 + r) * 9 + c] + redf[(1 * 256 + r) * 9 + c]
                      + redf[(2 * 256 + r) * 9 + c] + redf[(3 * 256 + r) * 9 + c];
        part[((size_t)chunk * 8192 + rgrp * 256 + r) * 9 + c] = s;
    }
}

// 256 blocks x 32 rows; reduction parallelized over all 256 threads
// (thread = (row, col)), so nch=32 partial sets stay cheap.
__global__ __launch_bounds__(256) void finish_kernel(
    const float* __restrict__ x,
    const float* __restrict__ Zw, const float* __restrict__ Zb,
    const float* __restrict__ part, float* __restrict__ out, int nch)
{
    __shared__ float Zs[32 * 9];
    __shared__ float Zl[32];
    __shared__ float zw_s[384];
    __shared__ float zb_s[48];
    const int tid = threadIdx.x;
    const int r0 = blockIdx.x * 32;

    for (int i = tid; i < 384; i += 256) zw_s[i] = Zw[i];
    if (tid < 48) zb_s[tid] = Zb[tid];

    // phase 1: thread = (row r = tid>>3, col c = tid&7); c==0 also sums l
    {
        const int r = tid >> 3, c = tid & 7;
        float a = 0.f, l = 0.f;
        #pragma unroll 4
        for (int ch = 0; ch < nch; ch++) {
            const float* p = part + ((size_t)ch * 8192 + r0 + r) * 9;
            a += p[c];
            if (c == 0) l += p[8];
        }
        if (c == 0) Zl[r] = l;
        __syncthreads();
        Zs[r * 9 + c] = a * (1.0f / Zl[r]);
    }
    __syncthreads();

    for (int e = tid; e < 32 * 48; e += 256) {
        const int r = e / 48, c = e - r * 48;
        float o = x[r0 * 48 + e] + zb_s[c];
        #pragma unroll
        for (int k = 0; k < 8; k++) o = fmaf(Zs[r * 9 + k], zw_s[k * 48 + c], o);
        out[r0 * 48 + e] = o;
    }
}

extern "C" void kernel_launch(void* const* d_in, const int* in_sizes, int n_in,
                              void* d_out, int out_size, void* d_ws, size_t ws_size,
                              hipStream_t stream) {
    const float* x  = (const float*)d_in[0];
    const float* Kw = (const float*)d_in[1];
    const float* Kb = (const float*)d_in[2];
    const float* Qw = (const float*)d_in[3];
    const float* Qb = (const float*)d_in[4];
    const float* Vw = (const float*)d_in[5];
    const float* Vb = (const float*)d_in[6];
    const float* Zw = (const float*)d_in[7];
    const float* Zb = (const float*)d_in[8];
    float* out = (float*)d_out;

    float* ws = (float*)d_ws;
    unsigned* Xksf16 = (unsigned*)ws;
    unsigned* QV     = (unsigned*)(ws + QV_OFF);
    float* bmax      = ws + BMAX_OFF;
    float* part      = ws + PART_OFF;

    int nch = 32;
    const size_t avail = ws_size / 4;
    while (nch > 1 && (size_t)PART_OFF + (size_t)nch * 8192 * 9 > avail) nch >>= 1;
    const int ppw = 1024 / nch;   // j-pairs per wave (4096 pairs / (nch*4 waves))

    proj_kernel<<<256, 256, 0, stream>>>(x, Kw, Kb, Qw, Qb, Vw, Vb,
                                         Xksf16, QV, bmax);
    attn_kernel<<<32 * nch, 256, 0, stream>>>(Xksf16, QV, bmax, part, ppw);
    finish_kernel<<<256, 256, 0, stream>>>(x, Zw, Zb, part, out, nch);
}